// Round 17
// baseline (160.143 us; speedup 1.0000x reference)
//
#include <hip/hip_runtime.h>
#include <stdint.h>

// Problem constants
#define T_TOK   16384      // B*S
#define H_DIM   1024
#define IE_DIM  512
#define E_NUM   8
#define V_MAX   100000

typedef __attribute__((ext_vector_type(8))) short bf16x8;
typedef __attribute__((ext_vector_type(4))) float f32x4;
typedef unsigned long long ull;

__device__ __forceinline__ unsigned short f2bf(float f) {
  union { float f; unsigned u; } v; v.f = f;
  unsigned r = v.u + 0x7fffu + ((v.u >> 16) & 1u);
  return (unsigned short)(r >> 16);
}

__device__ __forceinline__ void gload16(const void* g, void* l) {
  __builtin_amdgcn_global_load_lds(
      (const __attribute__((address_space(1))) unsigned int*)g,
      (__attribute__((address_space(3))) unsigned int*)(unsigned int)(uintptr_t)l,
      16, 0, 0);
}

// ---------------- route: 16 tokens/block, eid + rank + per-block histogram ----------------
__global__ __launch_bounds__(256) void k_route(
    const float* __restrict__ mu, const int* __restrict__ tok,
    const float* __restrict__ mrw, int* __restrict__ eid,
    int* __restrict__ rank, int* __restrict__ blockCnt) {
  __shared__ int cnt[8];
  __shared__ int eL[16];
  int tid = threadIdx.x;
  if (tid < 8) cnt[tid] = 0;
  int wv = blockIdx.x * 4 + (tid >> 6);
  int t0 = wv * 4;
  int lane = tid & 63;
  const float4* mrw4 = (const float4*)mrw;

  float acc[4][E_NUM];
#pragma unroll
  for (int i = 0; i < 4; i++)
#pragma unroll
    for (int e = 0; e < E_NUM; e++) acc[i][e] = 0.f;

#pragma unroll
  for (int j = 0; j < 4; j++) {
    int idx = lane + 64 * j;
    float4 wr[E_NUM];
#pragma unroll
    for (int e = 0; e < E_NUM; e++) wr[e] = mrw4[e * 256 + idx];
#pragma unroll
    for (int i = 0; i < 4; i++) {
      float4 m = ((const float4*)(mu + (size_t)(t0 + i) * H_DIM))[idx];
#pragma unroll
      for (int e = 0; e < E_NUM; e++)
        acc[i][e] += m.x * wr[e].x + m.y * wr[e].y + m.z * wr[e].z + m.w * wr[e].w;
    }
  }
#pragma unroll
  for (int i = 0; i < 4; i++)
#pragma unroll
    for (int e = 0; e < E_NUM; e++)
#pragma unroll
      for (int off = 32; off >= 1; off >>= 1)
        acc[i][e] += __shfl_xor(acc[i][e], off, 64);

  __syncthreads();
#pragma unroll
  for (int i = 0; i < 4; i++) {
    int tv = tok[t0 + i];
    if (tv < 0) tv = 0;
    if (tv > V_MAX - 1) tv = V_MAX - 1;
    int base = tv & 7;
    int best = 0; float bs = -1e30f;
#pragma unroll
    for (int e = 0; e < E_NUM; e++) {
      float s = acc[i][e] + (e == base ? 10.f : 0.f);
      if (s > bs) { bs = s; best = e; }
    }
    if (lane == i) {
      eid[t0 + i] = best;
      eL[(tid >> 6) * 4 + i] = best;
      atomicAdd(&cnt[best], 1);
    }
  }
  __syncthreads();
  if (tid < 16) {
    int e = eL[tid];
    int r = 0;
    for (int j = 0; j < tid; j++) r += (eL[j] == e);
    rank[blockIdx.x * 16 + tid] = r;
  }
  if (tid < 8) blockCnt[blockIdx.x * 8 + tid] = cnt[tid];
}

// ---------------- scan: packed 8x16-bit Hillis-Steele over 1024 blocks ----------------
__global__ __launch_bounds__(1024) void k_scan2(
    const int* __restrict__ blockCnt, int* __restrict__ blockBase,
    int* __restrict__ offsets, int* __restrict__ tileOff) {
  int b = threadIdx.x;
  __shared__ ull s0[1024], s1[1024];
  __shared__ int offL[8];
  const int4* p = (const int4*)(blockCnt + b * 8);
  int4 x0 = p[0], x1 = p[1];
  int c[8] = {x0.x, x0.y, x0.z, x0.w, x1.x, x1.y, x1.z, x1.w};
  ull v0 = (ull)c[0] | ((ull)c[1] << 16) | ((ull)c[2] << 32) | ((ull)c[3] << 48);
  ull v1 = (ull)c[4] | ((ull)c[5] << 16) | ((ull)c[6] << 32) | ((ull)c[7] << 48);
  s0[b] = v0; s1[b] = v1;
  __syncthreads();
  for (int st = 1; st < 1024; st <<= 1) {
    ull a0 = 0, a1 = 0;
    if (b >= st) { a0 = s0[b - st]; a1 = s1[b - st]; }
    __syncthreads();
    v0 += a0; v1 += a1;
    s0[b] = v0; s1[b] = v1;
    __syncthreads();
  }
  if (b == 1023) {
    int tot[8];
#pragma unroll
    for (int e = 0; e < 4; e++) tot[e] = (int)((v0 >> (16 * e)) & 0xFFFF);
#pragma unroll
    for (int e = 0; e < 4; e++) tot[4 + e] = (int)((v1 >> (16 * e)) & 0xFFFF);
    int s = 0, ts = 0;
    for (int e = 0; e < E_NUM; e++) {
      offsets[e] = s; offL[e] = s; tileOff[e] = ts;
      s += tot[e];
      ts += (tot[e] + 127) >> 7;     // 128-row M-tiles
    }
    offsets[E_NUM] = s; tileOff[E_NUM] = ts;
  }
  __syncthreads();
  int be[8];
#pragma unroll
  for (int e = 0; e < 4; e++)
    be[e] = offL[e] + (int)((v0 >> (16 * e)) & 0xFFFF) - c[e];
#pragma unroll
  for (int e = 0; e < 4; e++)
    be[4 + e] = offL[4 + e] + (int)((v1 >> (16 * e)) & 0xFFFF) - c[4 + e];
  int4* q = (int4*)(blockBase + b * 8);
  q[0] = make_int4(be[0], be[1], be[2], be[3]);
  q[1] = make_int4(be[4], be[5], be[6], be[7]);
}

// ---------------- transpose tile base computation ----------------
__device__ __forceinline__ void tr_bases(
    int g, const float* wg, const float* wu, const float* wd,
    unsigned short* WgT, unsigned short* WuT, unsigned short* WdT,
    const float*& s, unsigned short*& d, int& C, int& R) {
  int sel = g >> 10, blk = g & 1023;
  const float* src; unsigned short* dst;
  if (sel == 0)      { src = wg; dst = WgT; R = H_DIM; C = IE_DIM; }
  else if (sel == 1) { src = wu; dst = WuT; R = H_DIM; C = IE_DIM; }
  else               { src = wd; dst = WdT; R = IE_DIM; C = H_DIM; }
  int tpe = (R >> 6) * (C >> 6);   // 128
  int e = blk / tpe;
  int rem = blk % tpe;
  int tr = rem / (C >> 6);
  int tc = rem % (C >> 6);
  s = src + (size_t)e * R * C + (size_t)(tr * 64) * C + tc * 64;
  d = dst + (size_t)e * R * C + (size_t)(tc * 64) * R + tr * 64;
}

// ---------------- fused gather (blocks 0..1023, syncless) + pipelined transpose (1024..1791) ----------------
__global__ __launch_bounds__(256) void k_gathtr(
    const float* __restrict__ hs, const int* __restrict__ eid,
    const int* __restrict__ rank, const int* __restrict__ blockBase,
    int* __restrict__ tokofrow, unsigned short* __restrict__ Xs,
    const float* __restrict__ wg, const float* __restrict__ wu,
    const float* __restrict__ wd, unsigned short* __restrict__ WgT,
    unsigned short* __restrict__ WuT, unsigned short* __restrict__ WdT) {
  int tid = threadIdx.x;

  if (blockIdx.x < 1024) {
    // ---- gather: rank precomputed, no LDS, no syncs, waves independent ----
    int b = blockIdx.x;
    int w = tid >> 6, lane = tid & 63;
#pragma unroll
    for (int i = 0; i < 4; i++) {
      int li = w * 4 + i;
      int t = b * 16 + li;
      int e = eid[t];
      int pos = blockBase[b * 8 + e] + rank[t];
      if (lane == 0) tokofrow[pos] = t;
      const float4* src = (const float4*)(hs + (size_t)t * H_DIM);
      unsigned short* drow = Xs + (size_t)pos * H_DIM;
#pragma unroll
      for (int j = 0; j < 4; j++) {
        float4 v = src[lane + 64 * j];
        ushort4 bb;
        bb.x = f2bf(v.x); bb.y = f2bf(v.y); bb.z = f2bf(v.z); bb.w = f2bf(v.w);
        *(ushort4*)(drow + (lane + 64 * j) * 4) = bb;
      }
    }
  } else {
    // ---- transpose-convert: 4 tiles per block, 2 LDS buffers, pipelined ----
    __shared__ unsigned short lds[2][64][72];
    int base = (blockIdx.x - 1024) * 4;     // 768 blocks x 4 tiles = 3072
    int r0 = tid >> 4, c0 = (tid & 15) * 4;
    int oc = tid >> 2, ob = (tid & 3) * 16;
    float4 v0[4], v1[4];
    unsigned short* dS[2]; int RS[2];

#define TLOAD(g, vv, slot)                                                  \
  { const float* s_; unsigned short* d_; int C_, R_;                        \
    tr_bases(g, wg, wu, wd, WgT, WuT, WdT, s_, d_, C_, R_);                 \
    _Pragma("unroll") for (int i = 0; i < 4; i++)                           \
      vv[i] = *(const float4*)(s_ + (size_t)(r0 + i * 16) * C_ + c0);       \
    dS[slot] = d_; RS[slot] = R_; }

#define TWRITE(buf, vv)                                                     \
  { _Pragma("unroll") for (int i = 0; i < 4; i++) {                         \
      int r_ = r0 + i * 16;                                                 \
      lds[buf][r_][c0 + 0] = f2bf(vv[i].x);                                 \
      lds[buf][r_][c0 + 1] = f2bf(vv[i].y);                                 \
      lds[buf][r_][c0 + 2] = f2bf(vv[i].z);                                 \
      lds[buf][r_][c0 + 3] = f2bf(vv[i].w); } }

#define TSTORE(buf, slot)                                                   \
  { unsigned short tmp[16];                                                 \
    _Pragma("unroll") for (int i = 0; i < 16; i++) tmp[i] = lds[buf][ob + i][oc]; \
    uint4* dp_ = (uint4*)(dS[slot] + (size_t)oc * RS[slot] + ob);           \
    dp_[0] = ((uint4*)tmp)[0]; dp_[1] = ((uint4*)tmp)[1]; }

    // region 0: write(b0,t0); prefetch t1
    TLOAD(base + 0, v0, 0);
    TWRITE(0, v0);
    TLOAD(base + 1, v1, 1);
    __syncthreads();
    // region 1: store(b0); write(b1,t1); prefetch t2
    TSTORE(0, 0);
    TWRITE(1, v1);
    TLOAD(base + 2, v0, 0);
    __syncthreads();
    // region 2: store(b1); write(b0,t2); prefetch t3
    TSTORE(1, 1);
    TWRITE(0, v0);
    TLOAD(base + 3, v1, 1);
    __syncthreads();
    // region 3: store(b0); write(b1,t3)
    TSTORE(0, 0);
    TWRITE(1, v1);
    __syncthreads();
    // region 4: store(b1)
    TSTORE(1, 1);
#undef TLOAD
#undef TWRITE
#undef TSTORE
  }
}

// ---------------- GEMM1 (R7 proven): h = silu(X Wg) * (X Wu), bf16 out ----------------
// BM=128, BN=128, BK=32. 8 waves (2x4), wave tile 64x32 dual-acc.
// 3-buffer LDS, prefetch depth 2, counted vmcnt(3). XCD swizzle + setprio.
__global__ __launch_bounds__(512) void k_gemm1(
    const unsigned short* __restrict__ Xs,
    const unsigned short* __restrict__ WgT,
    const unsigned short* __restrict__ WuT,
    unsigned short* __restrict__ Hb,
    const int* __restrict__ offsets, const int* __restrict__ tileOff) {
  // bijective XCD swizzle for nwg=540: q=67, r=4
  int bid0 = blockIdx.x;
  int xcd = bid0 & 7, seq = bid0 >> 3;
  int wg = (xcd < 4 ? xcd * 68 : 272 + (xcd - 4) * 67) + seq;
  int nt = wg & 3;
  int mlin = wg >> 2;
  if (mlin >= tileOff[E_NUM]) return;
  int e = 0;
#pragma unroll
  for (int i = 1; i < E_NUM; i++)
    if (mlin >= tileOff[i]) e = i;
  int mtile = mlin - tileOff[e];
  int segStart = offsets[e], segEnd = offsets[e + 1];
  int M = segEnd - segStart;

  __shared__ unsigned short Alds[3][128 * 32];
  __shared__ unsigned short Bglds[3][128 * 32];
  __shared__ unsigned short Bulds[3][128 * 32];

  int tid = threadIdx.x;
  int lane = tid & 63;
  int w = tid >> 6;
  int wm = w >> 2;   // 0..1
  int wn = w & 3;    // 0..3

  f32x4 accg[4][2], accu[4][2];
#pragma unroll
  for (int i = 0; i < 4; i++)
#pragma unroll
    for (int j = 0; j < 2; j++) {
      accg[i][j] = (f32x4)(0.f);
      accu[i][j] = (f32x4)(0.f);
    }

  int sr = tid >> 2;            // 0..127
  int sc = tid & 3;
  int scc = sc ^ ((sr >> 1) & 3);   // involution, mirrored on read
  int grow = mtile * 128 + sr;
  if (grow > M - 1) grow = M - 1;
  const unsigned short* Arow = Xs + (size_t)(segStart + grow) * H_DIM + scc * 8;
  const unsigned short* Bgrow =
      WgT + (size_t)e * IE_DIM * H_DIM + (size_t)(nt * 128 + sr) * H_DIM + scc * 8;
  const unsigned short* Burow =
      WuT + (size_t)e * IE_DIM * H_DIM + (size_t)(nt * 128 + sr) * H_DIM + scc * 8;

#define STAGE1(buf, k0)                                            \
  {                                                                \
    gload16(Arow + (k0), (char*)Alds[buf] + tid * 16);             \
    gload16(Bgrow + (k0), (char*)Bglds[buf] + tid * 16);           \
    gload16(Burow + (k0), (char*)Bulds[buf] + tid * 16);           \
  }

  int kc = lane >> 4;           // 0..3
  int arow[4], browv[2];
#pragma unroll
  for (int mf = 0; mf < 4; mf++) arow[mf] = wm * 64 + mf * 16 + (lane & 15);
#pragma unroll
  for (int nf = 0; nf < 2; nf++) browv[nf] = wn * 32 + nf * 16 + (lane & 15);

  const int NT = H_DIM / 32;    // 32
  STAGE1(0, 0);
  STAGE1(1, 32);                // 6 loads in flight

  int cur = 0;
  for (int t = 0; t < NT; t++) {
    asm volatile("s_waitcnt vmcnt(3)" ::: "memory");
    __builtin_amdgcn_s_barrier();
    __builtin_amdgcn_sched_barrier(0);
    int tn = t + 2; if (tn >= NT) tn -= NT;
    int nbuf = cur + 2; if (nbuf >= 3) nbuf -= 3;
    STAGE1(nbuf, tn * 32);

    bf16x8 a[4], bg[2], bu[2];
#pragma unroll
    for (int mf = 0; mf < 4; mf++) {
      int row = arow[mf];
      int byte = row * 64 + ((kc ^ ((row >> 1) & 3)) << 4);
      a[mf] = *(const bf16x8*)((const char*)Alds[cur] + byte);
    }
#pragma unroll
    for (int nf = 0; nf < 2; nf++) {
      int row = browv[nf];
      int byte = row * 64 + ((kc ^ ((row >> 1) & 3)) << 4);
      bg[nf] = *(const bf16x8*)((const char*)Bglds[cur] + byte);
      bu[nf] = *(const bf16x8*)((const char*)Bulds[cur] + byte);
    }
    __builtin_amdgcn_s_setprio(1);
#pragma unroll
    for (int mf = 0; mf < 4; mf++)
#pragma unroll
      for (int nf = 0; nf < 2; nf++) {
        accg[mf][nf] = __builtin_amdgcn_mfma_f32_16x16x32_bf16(
            a[mf], bg[nf], accg[mf][nf], 0, 0, 0);
        accu[mf][nf] = __builtin_amdgcn_mfma_f32_16x16x32_bf16(
            a[mf], bu[nf], accu[mf][nf], 0, 0, 0);
      }
    __builtin_amdgcn_s_setprio(0);
    cur = (cur + 1 == 3) ? 0 : cur + 1;
  }
#undef STAGE1
  asm volatile("s_waitcnt vmcnt(0)" ::: "memory");

  int rowBase = segStart + mtile * 128 + wm * 64;
#pragma unroll
  for (int mf = 0; mf < 4; mf++)
#pragma unroll
    for (int nf = 0; nf < 2; nf++) {
      int col = nt * 128 + wn * 32 + nf * 16 + (lane & 15);
#pragma unroll
      for (int j = 0; j < 4; j++) {
        int r = rowBase + mf * 16 + (lane >> 4) * 4 + j;
        if (r < segEnd) {
          float g = accg[mf][nf][j];
          float u = accu[mf][nf][j];
          float h = (g / (1.f + __expf(-g))) * u;
          Hb[(size_t)r * IE_DIM + col] = f2bf(h);
        }
      }
    }
}

// ---------------- GEMM2 (R7 proven): out[tok] = h Wd, fp32 scatter ----------------
__global__ __launch_bounds__(512) void k_gemm2(
    const unsigned short* __restrict__ Hb,
    const unsigned short* __restrict__ WdT,
    float* __restrict__ out,
    const int* __restrict__ offsets, const int* __restrict__ tileOff,
    const int* __restrict__ tokofrow) {
  // bijective XCD swizzle for nwg=1080: q=135, r=0
  int bid0 = blockIdx.x;
  int wg = (bid0 & 7) * 135 + (bid0 >> 3);
  int nt = wg & 7;
  int mlin = wg >> 3;
  if (mlin >= tileOff[E_NUM]) return;
  int e = 0;
#pragma unroll
  for (int i = 1; i < E_NUM; i++)
    if (mlin >= tileOff[i]) e = i;
  int mtile = mlin - tileOff[e];
  int segStart = offsets[e], segEnd = offsets[e + 1];
  int M = segEnd - segStart;

  __shared__ unsigned short Alds[3][128 * 32];
  __shared__ unsigned short Blds[3][128 * 32];

  int tid = threadIdx.x;
  int lane = tid & 63;
  int w = tid >> 6;
  int wm = w >> 2;
  int wn = w & 3;

  f32x4 acc[4][2];
#pragma unroll
  for (int i = 0; i < 4; i++)
#pragma unroll
    for (int j = 0; j < 2; j++) acc[i][j] = (f32x4)(0.f);

  int sr = tid >> 2;
  int sc = tid & 3;
  int scc = sc ^ ((sr >> 1) & 3);
  int grow = mtile * 128 + sr;
  if (grow > M - 1) grow = M - 1;
  const unsigned short* Arow = Hb + (size_t)(segStart + grow) * IE_DIM + scc * 8;
  const unsigned short* Brow =
      WdT + (size_t)e * H_DIM * IE_DIM + (size_t)(nt * 128 + sr) * IE_DIM + scc * 8;

#define STAGE2(buf, k0)                                            \
  {                                                                \
    gload16(Arow + (k0), (char*)Alds[buf] + tid * 16);             \
    gload16(Brow + (k0), (char*)Blds[buf] + tid * 16);             \
  }

  int kc = lane >> 4;
  int arow[4], browv[2];
#pragma unroll
  for (int mf = 0; mf < 4; mf++) arow[mf] = wm * 64 + mf * 16 + (lane & 15);
#pragma unroll
  for (int nf = 0; nf < 2; nf++) browv[nf] = wn * 32 + nf * 16 + (lane & 15);

  const int NT = IE_DIM / 32;
  STAGE2(0, 0);
  STAGE2(1, 32);

  int cur = 0;
  for (int t = 0; t < NT; t++) {
    asm volatile("s_waitcnt vmcnt(2)" ::: "memory");
    __builtin_amdgcn_s_barrier();
    __builtin_amdgcn_sched_barrier(0);
    int tn = t + 2; if (tn >= NT) tn -= NT;
    int nbuf = cur + 2; if (nbuf >= 3) nbuf -= 3;
    STAGE2(nbuf, tn * 32);

    bf16x8 a[4], b[2];
#pragma unroll
    for (int mf = 0; mf < 4; mf++) {
      int row = arow[mf];
      int byte = row * 64 + ((kc ^ ((row >> 1) & 3)) << 4);
      a[mf] = *(const bf16x8*)((const char*)Alds[cur] + byte);
    }
#pragma unroll
    for (int nf = 0; nf < 2; nf++) {
      int row = browv[nf];
      int byte = row * 64 + ((kc ^ ((row >> 1) & 3)) << 4);
      b[nf] = *(const bf16x8*)((const char*)Blds[cur] + byte);
    }
    __builtin_amdgcn_s_setprio(1);
#pragma unroll
    for (int mf = 0; mf < 4; mf++)
#pragma unroll
      for (int nf = 0; nf < 2; nf++)
        acc[mf][nf] = __builtin_amdgcn_mfma_f32_16x16x32_bf16(
            a[mf], b[nf], acc[mf][nf], 0, 0, 0);
    __builtin_amdgcn_s_setprio(0);
    cur = (cur + 1 == 3) ? 0 : cur + 1;
  }
#undef STAGE2
  asm volatile("s_waitcnt vmcnt(0)" ::: "memory");

  int rowBase = segStart + mtile * 128 + wm * 64;
#pragma unroll
  for (int mf = 0; mf < 4; mf++)
#pragma unroll
    for (int nf = 0; nf < 2; nf++) {
      int col = nt * 128 + wn * 32 + nf * 16 + (lane & 15);
#pragma unroll
      for (int j = 0; j < 4; j++) {
        int r = rowBase + mf * 16 + (lane >> 4) * 4 + j;
        if (r < segEnd) {
          int t = tokofrow[r];
          out[(size_t)t * H_DIM + col] = acc[mf][nf][j];
        }
      }
    }
}

// ---------------- workspace layout (bytes) ----------------
#define WS_XS    ((size_t)0)             // 32MB
#define WS_WGT   ((size_t)33554432)      // 8MB
#define WS_WUT   ((size_t)41943040)      // 8MB
#define WS_WDT   ((size_t)50331648)      // 8MB
#define WS_HB    ((size_t)58720256)      // 16MB
#define WS_EID   ((size_t)75497472)      // 64KB
#define WS_TOK   ((size_t)75563008)      // 64KB
#define WS_OFF   ((size_t)75628544)      // offsets/tileOff (1KB)
#define WS_BC    ((size_t)75629568)      // blockCnt 32KB
#define WS_BB    ((size_t)75662336)      // blockBase 32KB
#define WS_RK    ((size_t)75695104)      // rank[T] 64KB

extern "C" void kernel_launch(void* const* d_in, const int* in_sizes, int n_in,
                              void* d_out, int out_size, void* d_ws, size_t ws_size,
                              hipStream_t stream) {
  const float* hs  = (const float*)d_in[0];
  const int*   tok = (const int*)d_in[1];
  const float* mu  = (const float*)d_in[2];
  const float* wg  = (const float*)d_in[3];
  const float* wu  = (const float*)d_in[4];
  const float* wd  = (const float*)d_in[5];
  const float* mrw = (const float*)d_in[6];
  float* out = (float*)d_out;
  char* ws = (char*)d_ws;

  unsigned short* Xs  = (unsigned short*)(ws + WS_XS);
  unsigned short* WgT = (unsigned short*)(ws + WS_WGT);
  unsigned short* WuT = (unsigned short*)(ws + WS_WUT);
  unsigned short* WdT = (unsigned short*)(ws + WS_WDT);
  unsigned short* Hb  = (unsigned short*)(ws + WS_HB);
  int* eid      = (int*)(ws + WS_EID);
  int* tokofrow = (int*)(ws + WS_TOK);
  int* offsets  = (int*)(ws + WS_OFF);   // [9]
  int* tileOff  = offsets + 16;          // [9]  128-gran
  int* blockCnt = (int*)(ws + WS_BC);    // [1024][8]
  int* blockBase= (int*)(ws + WS_BB);    // [1024][8]
  int* rank     = (int*)(ws + WS_RK);    // [T]

  k_route<<<1024, 256, 0, stream>>>(mu, tok, mrw, eid, rank, blockCnt);
  k_scan2<<<1, 1024, 0, stream>>>(blockCnt, blockBase, offsets, tileOff);
  k_gathtr<<<1792, 256, 0, stream>>>(hs, eid, rank, blockBase, tokofrow, Xs,
                                     wg, wu, wd, WgT, WuT, WdT);
  // gemm1: worst-case M-tiles(128) = 135; x4 n-tiles = 540
  k_gemm1<<<135 * 4, 512, 0, stream>>>(Xs, WgT, WuT, Hb, offsets, tileOff);
  // gemm2: 135 x8 n-tiles = 1080
  k_gemm2<<<135 * 8, 512, 0, stream>>>(Hb, WdT, out, offsets, tileOff, tokofrow);
}

// Round 18
// 154.926 us; speedup vs baseline: 1.0337x; 1.0337x over previous
//
#include <hip/hip_runtime.h>
#include <stdint.h>

// Problem constants
#define T_TOK   16384      // B*S
#define H_DIM   1024
#define IE_DIM  512
#define E_NUM   8
#define V_MAX   100000

typedef __attribute__((ext_vector_type(8))) short bf16x8;
typedef __attribute__((ext_vector_type(4))) float f32x4;
typedef unsigned long long ull;

__device__ __forceinline__ unsigned short f2bf(float f) {
  union { float f; unsigned u; } v; v.f = f;
  unsigned r = v.u + 0x7fffu + ((v.u >> 16) & 1u);
  return (unsigned short)(r >> 16);
}

__device__ __forceinline__ void gload16(const void* g, void* l) {
  __builtin_amdgcn_global_load_lds(
      (const __attribute__((address_space(1))) unsigned int*)g,
      (__attribute__((address_space(3))) unsigned int*)(unsigned int)(uintptr_t)l,
      16, 0, 0);
}

// ---------------- route: 16 tokens/block, eid + per-block histogram ----------------
__global__ __launch_bounds__(256) void k_route(
    const float* __restrict__ mu, const int* __restrict__ tok,
    const float* __restrict__ mrw, int* __restrict__ eid,
    int* __restrict__ blockCnt) {
  __shared__ int cnt[8];
  int tid = threadIdx.x;
  if (tid < 8) cnt[tid] = 0;
  int wv = blockIdx.x * 4 + (tid >> 6);
  int t0 = wv * 4;
  int lane = tid & 63;
  const float4* mrw4 = (const float4*)mrw;

  float acc[4][E_NUM];
#pragma unroll
  for (int i = 0; i < 4; i++)
#pragma unroll
    for (int e = 0; e < E_NUM; e++) acc[i][e] = 0.f;

#pragma unroll
  for (int j = 0; j < 4; j++) {
    int idx = lane + 64 * j;
    float4 wr[E_NUM];
#pragma unroll
    for (int e = 0; e < E_NUM; e++) wr[e] = mrw4[e * 256 + idx];
#pragma unroll
    for (int i = 0; i < 4; i++) {
      float4 m = ((const float4*)(mu + (size_t)(t0 + i) * H_DIM))[idx];
#pragma unroll
      for (int e = 0; e < E_NUM; e++)
        acc[i][e] += m.x * wr[e].x + m.y * wr[e].y + m.z * wr[e].z + m.w * wr[e].w;
    }
  }
#pragma unroll
  for (int i = 0; i < 4; i++)
#pragma unroll
    for (int e = 0; e < E_NUM; e++)
#pragma unroll
      for (int off = 32; off >= 1; off >>= 1)
        acc[i][e] += __shfl_xor(acc[i][e], off, 64);

  __syncthreads();
#pragma unroll
  for (int i = 0; i < 4; i++) {
    int tv = tok[t0 + i];
    if (tv < 0) tv = 0;
    if (tv > V_MAX - 1) tv = V_MAX - 1;
    int base = tv & 7;
    int best = 0; float bs = -1e30f;
#pragma unroll
    for (int e = 0; e < E_NUM; e++) {
      float s = acc[i][e] + (e == base ? 10.f : 0.f);
      if (s > bs) { bs = s; best = e; }
    }
    if (lane == i) {
      eid[t0 + i] = best;
      atomicAdd(&cnt[best], 1);
    }
  }
  __syncthreads();
  if (tid < 8) blockCnt[blockIdx.x * 8 + tid] = cnt[tid];
}

// ---------------- scan: packed 8x16-bit Hillis-Steele over 1024 blocks ----------------
__global__ __launch_bounds__(1024) void k_scan2(
    const int* __restrict__ blockCnt, int* __restrict__ blockBase,
    int* __restrict__ offsets, int* __restrict__ tileOff) {
  int b = threadIdx.x;
  __shared__ ull s0[1024], s1[1024];
  __shared__ int offL[8];
  const int4* p = (const int4*)(blockCnt + b * 8);
  int4 x0 = p[0], x1 = p[1];
  int c[8] = {x0.x, x0.y, x0.z, x0.w, x1.x, x1.y, x1.z, x1.w};
  ull v0 = (ull)c[0] | ((ull)c[1] << 16) | ((ull)c[2] << 32) | ((ull)c[3] << 48);
  ull v1 = (ull)c[4] | ((ull)c[5] << 16) | ((ull)c[6] << 32) | ((ull)c[7] << 48);
  s0[b] = v0; s1[b] = v1;
  __syncthreads();
  for (int st = 1; st < 1024; st <<= 1) {
    ull a0 = 0, a1 = 0;
    if (b >= st) { a0 = s0[b - st]; a1 = s1[b - st]; }
    __syncthreads();
    v0 += a0; v1 += a1;
    s0[b] = v0; s1[b] = v1;
    __syncthreads();
  }
  if (b == 1023) {
    int tot[8];
#pragma unroll
    for (int e = 0; e < 4; e++) tot[e] = (int)((v0 >> (16 * e)) & 0xFFFF);
#pragma unroll
    for (int e = 0; e < 4; e++) tot[4 + e] = (int)((v1 >> (16 * e)) & 0xFFFF);
    int s = 0, ts = 0;
    for (int e = 0; e < E_NUM; e++) {
      offsets[e] = s; offL[e] = s; tileOff[e] = ts;
      s += tot[e];
      ts += (tot[e] + 127) >> 7;     // 128-row M-tiles
    }
    offsets[E_NUM] = s; tileOff[E_NUM] = ts;
  }
  __syncthreads();
  int be[8];
#pragma unroll
  for (int e = 0; e < 4; e++)
    be[e] = offL[e] + (int)((v0 >> (16 * e)) & 0xFFFF) - c[e];
#pragma unroll
  for (int e = 0; e < 4; e++)
    be[4 + e] = offL[4 + e] + (int)((v1 >> (16 * e)) & 0xFFFF) - c[4 + e];
  int4* q = (int4*)(blockBase + b * 8);
  q[0] = make_int4(be[0], be[1], be[2], be[3]);
  q[1] = make_int4(be[4], be[5], be[6], be[7]);
}

// ---------------- fused gather (blocks 0..1023) + weight transpose (1024..4095) ----------------
__global__ __launch_bounds__(256) void k_gathtr(
    const float* __restrict__ hs, const int* __restrict__ eid,
    const int* __restrict__ blockBase, int* __restrict__ tokofrow,
    unsigned short* __restrict__ Xs,
    const float* __restrict__ wg, const float* __restrict__ wu,
    const float* __restrict__ wd, unsigned short* __restrict__ WgT,
    unsigned short* __restrict__ WuT, unsigned short* __restrict__ WdT) {
  __shared__ unsigned short lds[64][72];
  int tid = threadIdx.x;

  if (blockIdx.x < 1024) {
    // ---- gather: deterministic rank, no atomics ----
    int b = blockIdx.x;
    int* eL = (int*)&lds[0][0];
    int* posL = eL + 16;
    if (tid < 16) eL[tid] = eid[b * 16 + tid];
    __syncthreads();
    if (tid < 16) {
      int e = eL[tid];
      int r = 0;
      for (int j = 0; j < tid; j++) r += (eL[j] == e);
      int pos = blockBase[b * 8 + e] + r;
      posL[tid] = pos;
      tokofrow[pos] = b * 16 + tid;
    }
    __syncthreads();
    int w = tid >> 6, lane = tid & 63;
#pragma unroll
    for (int i = 0; i < 4; i++) {
      int li = w * 4 + i;
      int t = b * 16 + li;
      int pos = posL[li];
      const float4* src = (const float4*)(hs + (size_t)t * H_DIM);
      unsigned short* drow = Xs + (size_t)pos * H_DIM;
#pragma unroll
      for (int j = 0; j < 4; j++) {
        float4 v = src[lane + 64 * j];
        ushort4 bb;
        bb.x = f2bf(v.x); bb.y = f2bf(v.y); bb.z = f2bf(v.z); bb.w = f2bf(v.w);
        *(ushort4*)(drow + (lane + 64 * j) * 4) = bb;
      }
    }
  } else {
    // ---- transpose-convert fp32 [R][C] -> bf16 [C][R] ----
    int sel = (blockIdx.x - 1024) >> 10;
    int blk = blockIdx.x & 1023;
    const float* src; unsigned short* dst; int R, C;
    if (sel == 0)      { src = wg; dst = WgT; R = H_DIM; C = IE_DIM; }
    else if (sel == 1) { src = wu; dst = WuT; R = H_DIM; C = IE_DIM; }
    else               { src = wd; dst = WdT; R = IE_DIM; C = H_DIM; }
    int tpe = (R >> 6) * (C >> 6);
    int e = blk / tpe;
    int rem = blk % tpe;
    int tr = rem / (C >> 6);
    int tc = rem % (C >> 6);
    const float* s = src + (size_t)e * R * C;
    unsigned short* d = dst + (size_t)e * R * C;
    int r0 = tid >> 4;
    int c0 = (tid & 15) * 4;
#pragma unroll
    for (int i = 0; i < 4; i++) {
      int r = r0 + i * 16;
      float4 v = *(const float4*)(s + (size_t)(tr * 64 + r) * C + tc * 64 + c0);
      lds[r][c0 + 0] = f2bf(v.x); lds[r][c0 + 1] = f2bf(v.y);
      lds[r][c0 + 2] = f2bf(v.z); lds[r][c0 + 3] = f2bf(v.w);
    }
    __syncthreads();
    int oc = tid >> 2;
    int ob = (tid & 3) * 16;
    unsigned short tmp[16];
#pragma unroll
    for (int i = 0; i < 16; i++) tmp[i] = lds[ob + i][oc];
    uint4* dp = (uint4*)(d + (size_t)(tc * 64 + oc) * R + tr * 64 + ob);
    dp[0] = ((uint4*)tmp)[0];
    dp[1] = ((uint4*)tmp)[1];
  }
}

// ---------------- GEMM1 (R7 proven): h = silu(X Wg) * (X Wu), bf16 out ----------------
// BM=128, BN=128, BK=32. 8 waves (2x4), wave tile 64x32 dual-acc.
// 3-buffer LDS, prefetch depth 2, counted vmcnt(3). XCD swizzle + setprio.
__global__ __launch_bounds__(512) void k_gemm1(
    const unsigned short* __restrict__ Xs,
    const unsigned short* __restrict__ WgT,
    const unsigned short* __restrict__ WuT,
    unsigned short* __restrict__ Hb,
    const int* __restrict__ offsets, const int* __restrict__ tileOff) {
  // bijective XCD swizzle for nwg=540: q=67, r=4
  int bid0 = blockIdx.x;
  int xcd = bid0 & 7, seq = bid0 >> 3;
  int wg = (xcd < 4 ? xcd * 68 : 272 + (xcd - 4) * 67) + seq;
  int nt = wg & 3;
  int mlin = wg >> 2;
  if (mlin >= tileOff[E_NUM]) return;
  int e = 0;
#pragma unroll
  for (int i = 1; i < E_NUM; i++)
    if (mlin >= tileOff[i]) e = i;
  int mtile = mlin - tileOff[e];
  int segStart = offsets[e], segEnd = offsets[e + 1];
  int M = segEnd - segStart;

  __shared__ unsigned short Alds[3][128 * 32];
  __shared__ unsigned short Bglds[3][128 * 32];
  __shared__ unsigned short Bulds[3][128 * 32];

  int tid = threadIdx.x;
  int lane = tid & 63;
  int w = tid >> 6;
  int wm = w >> 2;   // 0..1
  int wn = w & 3;    // 0..3

  f32x4 accg[4][2], accu[4][2];
#pragma unroll
  for (int i = 0; i < 4; i++)
#pragma unroll
    for (int j = 0; j < 2; j++) {
      accg[i][j] = (f32x4)(0.f);
      accu[i][j] = (f32x4)(0.f);
    }

  int sr = tid >> 2;            // 0..127
  int sc = tid & 3;
  int scc = sc ^ ((sr >> 1) & 3);   // involution, mirrored on read
  int grow = mtile * 128 + sr;
  if (grow > M - 1) grow = M - 1;
  const unsigned short* Arow = Xs + (size_t)(segStart + grow) * H_DIM + scc * 8;
  const unsigned short* Bgrow =
      WgT + (size_t)e * IE_DIM * H_DIM + (size_t)(nt * 128 + sr) * H_DIM + scc * 8;
  const unsigned short* Burow =
      WuT + (size_t)e * IE_DIM * H_DIM + (size_t)(nt * 128 + sr) * H_DIM + scc * 8;

#define STAGE1(buf, k0)                                            \
  {                                                                \
    gload16(Arow + (k0), (char*)Alds[buf] + tid * 16);             \
    gload16(Bgrow + (k0), (char*)Bglds[buf] + tid * 16);           \
    gload16(Burow + (k0), (char*)Bulds[buf] + tid * 16);           \
  }

  int kc = lane >> 4;           // 0..3
  int arow[4], browv[2];
#pragma unroll
  for (int mf = 0; mf < 4; mf++) arow[mf] = wm * 64 + mf * 16 + (lane & 15);
#pragma unroll
  for (int nf = 0; nf < 2; nf++) browv[nf] = wn * 32 + nf * 16 + (lane & 15);

  const int NT = H_DIM / 32;    // 32
  STAGE1(0, 0);
  STAGE1(1, 32);                // 6 loads in flight

  int cur = 0;
  for (int t = 0; t < NT; t++) {
    asm volatile("s_waitcnt vmcnt(3)" ::: "memory");
    __builtin_amdgcn_s_barrier();
    __builtin_amdgcn_sched_barrier(0);
    int tn = t + 2; if (tn >= NT) tn -= NT;
    int nbuf = cur + 2; if (nbuf >= 3) nbuf -= 3;
    STAGE1(nbuf, tn * 32);

    bf16x8 a[4], bg[2], bu[2];
#pragma unroll
    for (int mf = 0; mf < 4; mf++) {
      int row = arow[mf];
      int byte = row * 64 + ((kc ^ ((row >> 1) & 3)) << 4);
      a[mf] = *(const bf16x8*)((const char*)Alds[cur] + byte);
    }
#pragma unroll
    for (int nf = 0; nf < 2; nf++) {
      int row = browv[nf];
      int byte = row * 64 + ((kc ^ ((row >> 1) & 3)) << 4);
      bg[nf] = *(const bf16x8*)((const char*)Bglds[cur] + byte);
      bu[nf] = *(const bf16x8*)((const char*)Bulds[cur] + byte);
    }
    __builtin_amdgcn_s_setprio(1);
#pragma unroll
    for (int mf = 0; mf < 4; mf++)
#pragma unroll
      for (int nf = 0; nf < 2; nf++) {
        accg[mf][nf] = __builtin_amdgcn_mfma_f32_16x16x32_bf16(
            a[mf], bg[nf], accg[mf][nf], 0, 0, 0);
        accu[mf][nf] = __builtin_amdgcn_mfma_f32_16x16x32_bf16(
            a[mf], bu[nf], accu[mf][nf], 0, 0, 0);
      }
    __builtin_amdgcn_s_setprio(0);
    cur = (cur + 1 == 3) ? 0 : cur + 1;
  }
#undef STAGE1
  asm volatile("s_waitcnt vmcnt(0)" ::: "memory");

  int rowBase = segStart + mtile * 128 + wm * 64;
#pragma unroll
  for (int mf = 0; mf < 4; mf++)
#pragma unroll
    for (int nf = 0; nf < 2; nf++) {
      int col = nt * 128 + wn * 32 + nf * 16 + (lane & 15);
#pragma unroll
      for (int j = 0; j < 4; j++) {
        int r = rowBase + mf * 16 + (lane >> 4) * 4 + j;
        if (r < segEnd) {
          float g = accg[mf][nf][j];
          float u = accu[mf][nf][j];
          float h = (g / (1.f + __expf(-g))) * u;
          Hb[(size_t)r * IE_DIM + col] = f2bf(h);
        }
      }
    }
}

// ---------------- GEMM2 (R7 proven): out[tok] = h Wd, fp32 scatter ----------------
__global__ __launch_bounds__(512) void k_gemm2(
    const unsigned short* __restrict__ Hb,
    const unsigned short* __restrict__ WdT,
    float* __restrict__ out,
    const int* __restrict__ offsets, const int* __restrict__ tileOff,
    const int* __restrict__ tokofrow) {
  // bijective XCD swizzle for nwg=1080: q=135, r=0
  int bid0 = blockIdx.x;
  int wg = (bid0 & 7) * 135 + (bid0 >> 3);
  int nt = wg & 7;
  int mlin = wg >> 3;
  if (mlin >= tileOff[E_NUM]) return;
  int e = 0;
#pragma unroll
  for (int i = 1; i < E_NUM; i++)
    if (mlin >= tileOff[i]) e = i;
  int mtile = mlin - tileOff[e];
  int segStart = offsets[e], segEnd = offsets[e + 1];
  int M = segEnd - segStart;

  __shared__ unsigned short Alds[3][128 * 32];
  __shared__ unsigned short Blds[3][128 * 32];

  int tid = threadIdx.x;
  int lane = tid & 63;
  int w = tid >> 6;
  int wm = w >> 2;
  int wn = w & 3;

  f32x4 acc[4][2];
#pragma unroll
  for (int i = 0; i < 4; i++)
#pragma unroll
    for (int j = 0; j < 2; j++) acc[i][j] = (f32x4)(0.f);

  int sr = tid >> 2;
  int sc = tid & 3;
  int scc = sc ^ ((sr >> 1) & 3);
  int grow = mtile * 128 + sr;
  if (grow > M - 1) grow = M - 1;
  const unsigned short* Arow = Hb + (size_t)(segStart + grow) * IE_DIM + scc * 8;
  const unsigned short* Brow =
      WdT + (size_t)e * H_DIM * IE_DIM + (size_t)(nt * 128 + sr) * IE_DIM + scc * 8;

#define STAGE2(buf, k0)                                            \
  {                                                                \
    gload16(Arow + (k0), (char*)Alds[buf] + tid * 16);             \
    gload16(Brow + (k0), (char*)Blds[buf] + tid * 16);             \
  }

  int kc = lane >> 4;
  int arow[4], browv[2];
#pragma unroll
  for (int mf = 0; mf < 4; mf++) arow[mf] = wm * 64 + mf * 16 + (lane & 15);
#pragma unroll
  for (int nf = 0; nf < 2; nf++) browv[nf] = wn * 32 + nf * 16 + (lane & 15);

  const int NT = IE_DIM / 32;
  STAGE2(0, 0);
  STAGE2(1, 32);

  int cur = 0;
  for (int t = 0; t < NT; t++) {
    asm volatile("s_waitcnt vmcnt(2)" ::: "memory");
    __builtin_amdgcn_s_barrier();
    __builtin_amdgcn_sched_barrier(0);
    int tn = t + 2; if (tn >= NT) tn -= NT;
    int nbuf = cur + 2; if (nbuf >= 3) nbuf -= 3;
    STAGE2(nbuf, tn * 32);

    bf16x8 a[4], b[2];
#pragma unroll
    for (int mf = 0; mf < 4; mf++) {
      int row = arow[mf];
      int byte = row * 64 + ((kc ^ ((row >> 1) & 3)) << 4);
      a[mf] = *(const bf16x8*)((const char*)Alds[cur] + byte);
    }
#pragma unroll
    for (int nf = 0; nf < 2; nf++) {
      int row = browv[nf];
      int byte = row * 64 + ((kc ^ ((row >> 1) & 3)) << 4);
      b[nf] = *(const bf16x8*)((const char*)Blds[cur] + byte);
    }
    __builtin_amdgcn_s_setprio(1);
#pragma unroll
    for (int mf = 0; mf < 4; mf++)
#pragma unroll
      for (int nf = 0; nf < 2; nf++)
        acc[mf][nf] = __builtin_amdgcn_mfma_f32_16x16x32_bf16(
            a[mf], b[nf], acc[mf][nf], 0, 0, 0);
    __builtin_amdgcn_s_setprio(0);
    cur = (cur + 1 == 3) ? 0 : cur + 1;
  }
#undef STAGE2
  asm volatile("s_waitcnt vmcnt(0)" ::: "memory");

  int rowBase = segStart + mtile * 128 + wm * 64;
#pragma unroll
  for (int mf = 0; mf < 4; mf++)
#pragma unroll
    for (int nf = 0; nf < 2; nf++) {
      int col = nt * 128 + wn * 32 + nf * 16 + (lane & 15);
#pragma unroll
      for (int j = 0; j < 4; j++) {
        int r = rowBase + mf * 16 + (lane >> 4) * 4 + j;
        if (r < segEnd) {
          int t = tokofrow[r];
          out[(size_t)t * H_DIM + col] = acc[mf][nf][j];
        }
      }
    }
}

// ---------------- workspace layout (bytes) ----------------
#define WS_XS    ((size_t)0)             // 32MB
#define WS_WGT   ((size_t)33554432)      // 8MB
#define WS_WUT   ((size_t)41943040)      // 8MB
#define WS_WDT   ((size_t)50331648)      // 8MB
#define WS_HB    ((size_t)58720256)      // 16MB
#define WS_EID   ((size_t)75497472)      // 64KB
#define WS_TOK   ((size_t)75563008)      // 64KB
#define WS_OFF   ((size_t)75628544)      // offsets/tileOff (1KB)
#define WS_BC    ((size_t)75629568)      // blockCnt 32KB
#define WS_BB    ((size_t)75662336)      // blockBase 32KB

extern "C" void kernel_launch(void* const* d_in, const int* in_sizes, int n_in,
                              void* d_out, int out_size, void* d_ws, size_t ws_size,
                              hipStream_t stream) {
  const float* hs  = (const float*)d_in[0];
  const int*   tok = (const int*)d_in[1];
  const float* mu  = (const float*)d_in[2];
  const float* wg  = (const float*)d_in[3];
  const float* wu  = (const float*)d_in[4];
  const float* wd  = (const float*)d_in[5];
  const float* mrw = (const float*)d_in[6];
  float* out = (float*)d_out;
  char* ws = (char*)d_ws;

  unsigned short* Xs  = (unsigned short*)(ws + WS_XS);
  unsigned short* WgT = (unsigned short*)(ws + WS_WGT);
  unsigned short* WuT = (unsigned short*)(ws + WS_WUT);
  unsigned short* WdT = (unsigned short*)(ws + WS_WDT);
  unsigned short* Hb  = (unsigned short*)(ws + WS_HB);
  int* eid      = (int*)(ws + WS_EID);
  int* tokofrow = (int*)(ws + WS_TOK);
  int* offsets  = (int*)(ws + WS_OFF);   // [9]
  int* tileOff  = offsets + 16;          // [9]  128-gran
  int* blockCnt = (int*)(ws + WS_BC);    // [1024][8]
  int* blockBase= (int*)(ws + WS_BB);    // [1024][8]

  k_route<<<1024, 256, 0, stream>>>(mu, tok, mrw, eid, blockCnt);
  k_scan2<<<1, 1024, 0, stream>>>(blockCnt, blockBase, offsets, tileOff);
  k_gathtr<<<4096, 256, 0, stream>>>(hs, eid, blockBase, tokofrow, Xs,
                                     wg, wu, wd, WgT, WuT, WdT);
  // gemm1: worst-case M-tiles(128) = 135; x4 n-tiles = 540
  k_gemm1<<<135 * 4, 512, 0, stream>>>(Xs, WgT, WuT, Hb, offsets, tileOff);
  // gemm2: 135 x8 n-tiles = 1080
  k_gemm2<<<135 * 8, 512, 0, stream>>>(Hb, WdT, out, offsets, tileOff, tokofrow);
}

// Round 19
// 150.931 us; speedup vs baseline: 1.0610x; 1.0265x over previous
//
#include <hip/hip_runtime.h>
#include <stdint.h>

// Problem constants
#define T_TOK   16384      // B*S
#define H_DIM   1024
#define IE_DIM  512
#define E_NUM   8
#define V_MAX   100000

typedef __attribute__((ext_vector_type(8))) short bf16x8;
typedef __attribute__((ext_vector_type(4))) float f32x4;
typedef unsigned long long ull;

__device__ __forceinline__ unsigned short f2bf(float f) {
  union { float f; unsigned u; } v; v.f = f;
  unsigned r = v.u + 0x7fffu + ((v.u >> 16) & 1u);
  return (unsigned short)(r >> 16);
}

__device__ __forceinline__ void gload16(const void* g, void* l) {
  __builtin_amdgcn_global_load_lds(
      (const __attribute__((address_space(1))) unsigned int*)g,
      (__attribute__((address_space(3))) unsigned int*)(unsigned int)(uintptr_t)l,
      16, 0, 0);
}

// ---------------- route: 16 tokens/block, eid + per-block histogram ----------------
__global__ __launch_bounds__(256) void k_route(
    const float* __restrict__ mu, const int* __restrict__ tok,
    const float* __restrict__ mrw, int* __restrict__ eid,
    int* __restrict__ blockCnt) {
  __shared__ int cnt[8];
  int tid = threadIdx.x;
  if (tid < 8) cnt[tid] = 0;
  int wv = blockIdx.x * 4 + (tid >> 6);
  int t0 = wv * 4;
  int lane = tid & 63;
  const float4* mrw4 = (const float4*)mrw;

  float acc[4][E_NUM];
#pragma unroll
  for (int i = 0; i < 4; i++)
#pragma unroll
    for (int e = 0; e < E_NUM; e++) acc[i][e] = 0.f;

#pragma unroll
  for (int j = 0; j < 4; j++) {
    int idx = lane + 64 * j;
    float4 wr[E_NUM];
#pragma unroll
    for (int e = 0; e < E_NUM; e++) wr[e] = mrw4[e * 256 + idx];
#pragma unroll
    for (int i = 0; i < 4; i++) {
      float4 m = ((const float4*)(mu + (size_t)(t0 + i) * H_DIM))[idx];
#pragma unroll
      for (int e = 0; e < E_NUM; e++)
        acc[i][e] += m.x * wr[e].x + m.y * wr[e].y + m.z * wr[e].z + m.w * wr[e].w;
    }
  }
#pragma unroll
  for (int i = 0; i < 4; i++)
#pragma unroll
    for (int e = 0; e < E_NUM; e++)
#pragma unroll
      for (int off = 32; off >= 1; off >>= 1)
        acc[i][e] += __shfl_xor(acc[i][e], off, 64);

  __syncthreads();
#pragma unroll
  for (int i = 0; i < 4; i++) {
    int tv = tok[t0 + i];
    if (tv < 0) tv = 0;
    if (tv > V_MAX - 1) tv = V_MAX - 1;
    int base = tv & 7;
    int best = 0; float bs = -1e30f;
#pragma unroll
    for (int e = 0; e < E_NUM; e++) {
      float s = acc[i][e] + (e == base ? 10.f : 0.f);
      if (s > bs) { bs = s; best = e; }
    }
    if (lane == i) {
      eid[t0 + i] = best;
      atomicAdd(&cnt[best], 1);
    }
  }
  __syncthreads();
  if (tid < 8) blockCnt[blockIdx.x * 8 + tid] = cnt[tid];
}

// ---------------- scan: packed 8x16-bit Hillis-Steele over 1024 blocks ----------------
__global__ __launch_bounds__(1024) void k_scan2(
    const int* __restrict__ blockCnt, int* __restrict__ blockBase,
    int* __restrict__ offsets, int* __restrict__ tileOff) {
  int b = threadIdx.x;
  __shared__ ull s0[1024], s1[1024];
  __shared__ int offL[8];
  const int4* p = (const int4*)(blockCnt + b * 8);
  int4 x0 = p[0], x1 = p[1];
  int c[8] = {x0.x, x0.y, x0.z, x0.w, x1.x, x1.y, x1.z, x1.w};
  ull v0 = (ull)c[0] | ((ull)c[1] << 16) | ((ull)c[2] << 32) | ((ull)c[3] << 48);
  ull v1 = (ull)c[4] | ((ull)c[5] << 16) | ((ull)c[6] << 32) | ((ull)c[7] << 48);
  s0[b] = v0; s1[b] = v1;
  __syncthreads();
  for (int st = 1; st < 1024; st <<= 1) {
    ull a0 = 0, a1 = 0;
    if (b >= st) { a0 = s0[b - st]; a1 = s1[b - st]; }
    __syncthreads();
    v0 += a0; v1 += a1;
    s0[b] = v0; s1[b] = v1;
    __syncthreads();
  }
  if (b == 1023) {
    int tot[8];
#pragma unroll
    for (int e = 0; e < 4; e++) tot[e] = (int)((v0 >> (16 * e)) & 0xFFFF);
#pragma unroll
    for (int e = 0; e < 4; e++) tot[4 + e] = (int)((v1 >> (16 * e)) & 0xFFFF);
    int s = 0, ts = 0;
    for (int e = 0; e < E_NUM; e++) {
      offsets[e] = s; offL[e] = s; tileOff[e] = ts;
      s += tot[e];
      ts += (tot[e] + 127) >> 7;     // 128-row M-tiles
    }
    offsets[E_NUM] = s; tileOff[E_NUM] = ts;
  }
  __syncthreads();
  int be[8];
#pragma unroll
  for (int e = 0; e < 4; e++)
    be[e] = offL[e] + (int)((v0 >> (16 * e)) & 0xFFFF) - c[e];
#pragma unroll
  for (int e = 0; e < 4; e++)
    be[4 + e] = offL[4 + e] + (int)((v1 >> (16 * e)) & 0xFFFF) - c[4 + e];
  int4* q = (int4*)(blockBase + b * 8);
  q[0] = make_int4(be[0], be[1], be[2], be[3]);
  q[1] = make_int4(be[4], be[5], be[6], be[7]);
}

// ---------------- fused gather (blocks 0..1023) + wg/wu transpose (1024..3071) ----------------
__global__ __launch_bounds__(256) void k_gathtr(
    const float* __restrict__ hs, const int* __restrict__ eid,
    const int* __restrict__ blockBase, int* __restrict__ tokofrow,
    unsigned short* __restrict__ Xs,
    const float* __restrict__ wg, const float* __restrict__ wu,
    unsigned short* __restrict__ WgT, unsigned short* __restrict__ WuT) {
  __shared__ unsigned short lds[64][72];
  int tid = threadIdx.x;

  if (blockIdx.x < 1024) {
    // ---- gather: deterministic rank, no atomics ----
    int b = blockIdx.x;
    int* eL = (int*)&lds[0][0];
    int* posL = eL + 16;
    if (tid < 16) eL[tid] = eid[b * 16 + tid];
    __syncthreads();
    if (tid < 16) {
      int e = eL[tid];
      int r = 0;
      for (int j = 0; j < tid; j++) r += (eL[j] == e);
      int pos = blockBase[b * 8 + e] + r;
      posL[tid] = pos;
      tokofrow[pos] = b * 16 + tid;
    }
    __syncthreads();
    int w = tid >> 6, lane = tid & 63;
#pragma unroll
    for (int i = 0; i < 4; i++) {
      int li = w * 4 + i;
      int t = b * 16 + li;
      int pos = posL[li];
      const float4* src = (const float4*)(hs + (size_t)t * H_DIM);
      unsigned short* drow = Xs + (size_t)pos * H_DIM;
#pragma unroll
      for (int j = 0; j < 4; j++) {
        float4 v = src[lane + 64 * j];
        ushort4 bb;
        bb.x = f2bf(v.x); bb.y = f2bf(v.y); bb.z = f2bf(v.z); bb.w = f2bf(v.w);
        *(ushort4*)(drow + (lane + 64 * j) * 4) = bb;
      }
    }
  } else {
    // ---- transpose-convert fp32 [1024][512] -> bf16 [512][1024] (wg, wu only) ----
    int sel = (blockIdx.x - 1024) >> 10;   // 0 or 1
    int blk = blockIdx.x & 1023;
    const float* src; unsigned short* dst;
    const int R = H_DIM, C = IE_DIM;
    if (sel == 0) { src = wg; dst = WgT; }
    else          { src = wu; dst = WuT; }
    int tpe = (R >> 6) * (C >> 6);   // 128
    int e = blk / tpe;
    int rem = blk % tpe;
    int tr = rem / (C >> 6);
    int tc = rem % (C >> 6);
    const float* s = src + (size_t)e * R * C;
    unsigned short* d = dst + (size_t)e * R * C;
    int r0 = tid >> 4;
    int c0 = (tid & 15) * 4;
#pragma unroll
    for (int i = 0; i < 4; i++) {
      int r = r0 + i * 16;
      float4 v = *(const float4*)(s + (size_t)(tr * 64 + r) * C + tc * 64 + c0);
      lds[r][c0 + 0] = f2bf(v.x); lds[r][c0 + 1] = f2bf(v.y);
      lds[r][c0 + 2] = f2bf(v.z); lds[r][c0 + 3] = f2bf(v.w);
    }
    __syncthreads();
    int oc = tid >> 2;
    int ob = (tid & 3) * 16;
    unsigned short tmp[16];
#pragma unroll
    for (int i = 0; i < 16; i++) tmp[i] = lds[ob + i][oc];
    uint4* dp = (uint4*)(d + (size_t)(tc * 64 + oc) * R + tr * 64 + ob);
    dp[0] = ((uint4*)tmp)[0];
    dp[1] = ((uint4*)tmp)[1];
  }
}

// ---------------- GEMM1 (R7 proven) + Wd-transpose tail blocks ----------------
// blocks 0..539: h = silu(X Wg) * (X Wu). BM=128,BN=128,BK=32, 8 waves 64x32,
// 3-buffer depth-2 counted vmcnt(3), XCD swizzle, setprio.
// blocks 540..1051: Wd transpose (2 tiles per 512-thr block) — WdT needed only by gemm2,
// runs for free in gemm1's ragged-tail CU holes.
__global__ __launch_bounds__(512) void k_gemm1(
    const unsigned short* __restrict__ Xs,
    const unsigned short* __restrict__ WgT,
    const unsigned short* __restrict__ WuT,
    unsigned short* __restrict__ Hb,
    const int* __restrict__ offsets, const int* __restrict__ tileOff,
    const float* __restrict__ wd, unsigned short* __restrict__ WdT) {
  __shared__ unsigned short Alds[3][128 * 32];
  __shared__ unsigned short Bglds[3][128 * 32];
  __shared__ unsigned short Bulds[3][128 * 32];

  int bid0 = blockIdx.x;
  int tid = threadIdx.x;

  if (bid0 < 540) {
    // bijective XCD swizzle for nwg=540: q=67, r=4
    int xcd = bid0 & 7, seq = bid0 >> 3;
    int wg = (xcd < 4 ? xcd * 68 : 272 + (xcd - 4) * 67) + seq;
    int nt = wg & 3;
    int mlin = wg >> 2;
    if (mlin < tileOff[E_NUM]) {
      int e = 0;
#pragma unroll
      for (int i = 1; i < E_NUM; i++)
        if (mlin >= tileOff[i]) e = i;
      int mtile = mlin - tileOff[e];
      int segStart = offsets[e], segEnd = offsets[e + 1];
      int M = segEnd - segStart;

      int lane = tid & 63;
      int w = tid >> 6;
      int wm = w >> 2;   // 0..1
      int wn = w & 3;    // 0..3

      f32x4 accg[4][2], accu[4][2];
#pragma unroll
      for (int i = 0; i < 4; i++)
#pragma unroll
        for (int j = 0; j < 2; j++) {
          accg[i][j] = (f32x4)(0.f);
          accu[i][j] = (f32x4)(0.f);
        }

      int sr = tid >> 2;            // 0..127
      int sc = tid & 3;
      int scc = sc ^ ((sr >> 1) & 3);   // involution, mirrored on read
      int grow = mtile * 128 + sr;
      if (grow > M - 1) grow = M - 1;
      const unsigned short* Arow = Xs + (size_t)(segStart + grow) * H_DIM + scc * 8;
      const unsigned short* Bgrow =
          WgT + (size_t)e * IE_DIM * H_DIM + (size_t)(nt * 128 + sr) * H_DIM + scc * 8;
      const unsigned short* Burow =
          WuT + (size_t)e * IE_DIM * H_DIM + (size_t)(nt * 128 + sr) * H_DIM + scc * 8;

#define STAGE1(buf, k0)                                            \
  {                                                                \
    gload16(Arow + (k0), (char*)Alds[buf] + tid * 16);             \
    gload16(Bgrow + (k0), (char*)Bglds[buf] + tid * 16);           \
    gload16(Burow + (k0), (char*)Bulds[buf] + tid * 16);           \
  }

      int kc = lane >> 4;           // 0..3
      int arow[4], browv[2];
#pragma unroll
      for (int mf = 0; mf < 4; mf++) arow[mf] = wm * 64 + mf * 16 + (lane & 15);
#pragma unroll
      for (int nf = 0; nf < 2; nf++) browv[nf] = wn * 32 + nf * 16 + (lane & 15);

      const int NT = H_DIM / 32;    // 32
      STAGE1(0, 0);
      STAGE1(1, 32);                // 6 loads in flight

      int cur = 0;
      for (int t = 0; t < NT; t++) {
        asm volatile("s_waitcnt vmcnt(3)" ::: "memory");
        __builtin_amdgcn_s_barrier();
        __builtin_amdgcn_sched_barrier(0);
        int tn = t + 2; if (tn >= NT) tn -= NT;
        int nbuf = cur + 2; if (nbuf >= 3) nbuf -= 3;
        STAGE1(nbuf, tn * 32);

        bf16x8 a[4], bg[2], bu[2];
#pragma unroll
        for (int mf = 0; mf < 4; mf++) {
          int row = arow[mf];
          int byte = row * 64 + ((kc ^ ((row >> 1) & 3)) << 4);
          a[mf] = *(const bf16x8*)((const char*)Alds[cur] + byte);
        }
#pragma unroll
        for (int nf = 0; nf < 2; nf++) {
          int row = browv[nf];
          int byte = row * 64 + ((kc ^ ((row >> 1) & 3)) << 4);
          bg[nf] = *(const bf16x8*)((const char*)Bglds[cur] + byte);
          bu[nf] = *(const bf16x8*)((const char*)Bulds[cur] + byte);
        }
        __builtin_amdgcn_s_setprio(1);
#pragma unroll
        for (int mf = 0; mf < 4; mf++)
#pragma unroll
          for (int nf = 0; nf < 2; nf++) {
            accg[mf][nf] = __builtin_amdgcn_mfma_f32_16x16x32_bf16(
                a[mf], bg[nf], accg[mf][nf], 0, 0, 0);
            accu[mf][nf] = __builtin_amdgcn_mfma_f32_16x16x32_bf16(
                a[mf], bu[nf], accu[mf][nf], 0, 0, 0);
          }
        __builtin_amdgcn_s_setprio(0);
        cur = (cur + 1 == 3) ? 0 : cur + 1;
      }
#undef STAGE1
      asm volatile("s_waitcnt vmcnt(0)" ::: "memory");

      int rowBase = segStart + mtile * 128 + wm * 64;
#pragma unroll
      for (int mf = 0; mf < 4; mf++)
#pragma unroll
        for (int nf = 0; nf < 2; nf++) {
          int col = nt * 128 + wn * 32 + nf * 16 + (lane & 15);
#pragma unroll
          for (int j = 0; j < 4; j++) {
            int r = rowBase + mf * 16 + (lane >> 4) * 4 + j;
            if (r < segEnd) {
              float g = accg[mf][nf][j];
              float u = accu[mf][nf][j];
              float h = (g / (1.f + __expf(-g))) * u;
              Hb[(size_t)r * IE_DIM + col] = f2bf(h);
            }
          }
        }
    }
  } else {
    // ---- Wd transpose: fp32 [512][1024] -> bf16 [1024][512]; 2 tiles/block ----
    unsigned short* pool = (unsigned short*)Alds;   // reuse 24KB (need 2x4608 shorts)
    int sub = tid >> 8;          // 0..1
    int stid = tid & 255;
    int g = (bid0 - 540) * 2 + sub;   // 0..1023
    int e2 = g >> 7;                  // 128 tiles per expert
    int rem = g & 127;
    int tr = rem >> 4;                // 0..7  (R=512)
    int tc = rem & 15;                // 0..15 (C=1024)
    const float* s = wd + (size_t)e2 * IE_DIM * H_DIM + (size_t)(tr * 64) * H_DIM + tc * 64;
    unsigned short* d = WdT + (size_t)e2 * IE_DIM * H_DIM + (size_t)(tc * 64) * IE_DIM + tr * 64;
    unsigned short* lds72 = pool + sub * 4608;   // [64][72]
    int r0 = stid >> 4, c0 = (stid & 15) * 4;
#pragma unroll
    for (int i = 0; i < 4; i++) {
      int r = r0 + i * 16;
      float4 v = *(const float4*)(s + (size_t)r * H_DIM + c0);
      lds72[r * 72 + c0 + 0] = f2bf(v.x);
      lds72[r * 72 + c0 + 1] = f2bf(v.y);
      lds72[r * 72 + c0 + 2] = f2bf(v.z);
      lds72[r * 72 + c0 + 3] = f2bf(v.w);
    }
    __syncthreads();
    int oc = stid >> 2;
    int ob = (stid & 3) * 16;
    unsigned short tmp[16];
#pragma unroll
    for (int i = 0; i < 16; i++) tmp[i] = lds72[(ob + i) * 72 + oc];
    uint4* dp = (uint4*)(d + (size_t)oc * IE_DIM + ob);
    dp[0] = ((uint4*)tmp)[0];
    dp[1] = ((uint4*)tmp)[1];
  }
}

// ---------------- GEMM2 (R7 proven): out[tok] = h Wd, fp32 scatter ----------------
__global__ __launch_bounds__(512) void k_gemm2(
    const unsigned short* __restrict__ Hb,
    const unsigned short* __restrict__ WdT,
    float* __restrict__ out,
    const int* __restrict__ offsets, const int* __restrict__ tileOff,
    const int* __restrict__ tokofrow) {
  // bijective XCD swizzle for nwg=1080: q=135, r=0
  int bid0 = blockIdx.x;
  int wg = (bid0 & 7) * 135 + (bid0 >> 3);
  int nt = wg & 7;
  int mlin = wg >> 3;
  if (mlin >= tileOff[E_NUM]) return;
  int e = 0;
#pragma unroll
  for (int i = 1; i < E_NUM; i++)
    if (mlin >= tileOff[i]) e = i;
  int mtile = mlin - tileOff[e];
  int segStart = offsets[e], segEnd = offsets[e + 1];
  int M = segEnd - segStart;

  __shared__ unsigned short Alds[3][128 * 32];
  __shared__ unsigned short Blds[3][128 * 32];

  int tid = threadIdx.x;
  int lane = tid & 63;
  int w = tid >> 6;
  int wm = w >> 2;
  int wn = w & 3;

  f32x4 acc[4][2];
#pragma unroll
  for (int i = 0; i < 4; i++)
#pragma unroll
    for (int j = 0; j < 2; j++) acc[i][j] = (f32x4)(0.f);

  int sr = tid >> 2;
  int sc = tid & 3;
  int scc = sc ^ ((sr >> 1) & 3);
  int grow = mtile * 128 + sr;
  if (grow > M - 1) grow = M - 1;
  const unsigned short* Arow = Hb + (size_t)(segStart + grow) * IE_DIM + scc * 8;
  const unsigned short* Brow =
      WdT + (size_t)e * H_DIM * IE_DIM + (size_t)(nt * 128 + sr) * IE_DIM + scc * 8;

#define STAGE2(buf, k0)                                            \
  {                                                                \
    gload16(Arow + (k0), (char*)Alds[buf] + tid * 16);             \
    gload16(Brow + (k0), (char*)Blds[buf] + tid * 16);             \
  }

  int kc = lane >> 4;
  int arow[4], browv[2];
#pragma unroll
  for (int mf = 0; mf < 4; mf++) arow[mf] = wm * 64 + mf * 16 + (lane & 15);
#pragma unroll
  for (int nf = 0; nf < 2; nf++) browv[nf] = wn * 32 + nf * 16 + (lane & 15);

  const int NT = IE_DIM / 32;
  STAGE2(0, 0);
  STAGE2(1, 32);

  int cur = 0;
  for (int t = 0; t < NT; t++) {
    asm volatile("s_waitcnt vmcnt(2)" ::: "memory");
    __builtin_amdgcn_s_barrier();
    __builtin_amdgcn_sched_barrier(0);
    int tn = t + 2; if (tn >= NT) tn -= NT;
    int nbuf = cur + 2; if (nbuf >= 3) nbuf -= 3;
    STAGE2(nbuf, tn * 32);

    bf16x8 a[4], b[2];
#pragma unroll
    for (int mf = 0; mf < 4; mf++) {
      int row = arow[mf];
      int byte = row * 64 + ((kc ^ ((row >> 1) & 3)) << 4);
      a[mf] = *(const bf16x8*)((const char*)Alds[cur] + byte);
    }
#pragma unroll
    for (int nf = 0; nf < 2; nf++) {
      int row = browv[nf];
      int byte = row * 64 + ((kc ^ ((row >> 1) & 3)) << 4);
      b[nf] = *(const bf16x8*)((const char*)Blds[cur] + byte);
    }
    __builtin_amdgcn_s_setprio(1);
#pragma unroll
    for (int mf = 0; mf < 4; mf++)
#pragma unroll
      for (int nf = 0; nf < 2; nf++)
        acc[mf][nf] = __builtin_amdgcn_mfma_f32_16x16x32_bf16(
            a[mf], b[nf], acc[mf][nf], 0, 0, 0);
    __builtin_amdgcn_s_setprio(0);
    cur = (cur + 1 == 3) ? 0 : cur + 1;
  }
#undef STAGE2
  asm volatile("s_waitcnt vmcnt(0)" ::: "memory");

  int rowBase = segStart + mtile * 128 + wm * 64;
#pragma unroll
  for (int mf = 0; mf < 4; mf++)
#pragma unroll
    for (int nf = 0; nf < 2; nf++) {
      int col = nt * 128 + wn * 32 + nf * 16 + (lane & 15);
#pragma unroll
      for (int j = 0; j < 4; j++) {
        int r = rowBase + mf * 16 + (lane >> 4) * 4 + j;
        if (r < segEnd) {
          int t = tokofrow[r];
          out[(size_t)t * H_DIM + col] = acc[mf][nf][j];
        }
      }
    }
}

// ---------------- workspace layout (bytes) ----------------
#define WS_XS    ((size_t)0)             // 32MB
#define WS_WGT   ((size_t)33554432)      // 8MB
#define WS_WUT   ((size_t)41943040)      // 8MB
#define WS_WDT   ((size_t)50331648)      // 8MB
#define WS_HB    ((size_t)58720256)      // 16MB
#define WS_EID   ((size_t)75497472)      // 64KB
#define WS_TOK   ((size_t)75563008)      // 64KB
#define WS_OFF   ((size_t)75628544)      // offsets/tileOff (1KB)
#define WS_BC    ((size_t)75629568)      // blockCnt 32KB
#define WS_BB    ((size_t)75662336)      // blockBase 32KB

extern "C" void kernel_launch(void* const* d_in, const int* in_sizes, int n_in,
                              void* d_out, int out_size, void* d_ws, size_t ws_size,
                              hipStream_t stream) {
  const float* hs  = (const float*)d_in[0];
  const int*   tok = (const int*)d_in[1];
  const float* mu  = (const float*)d_in[2];
  const float* wg  = (const float*)d_in[3];
  const float* wu  = (const float*)d_in[4];
  const float* wd  = (const float*)d_in[5];
  const float* mrw = (const float*)d_in[6];
  float* out = (float*)d_out;
  char* ws = (char*)d_ws;

  unsigned short* Xs  = (unsigned short*)(ws + WS_XS);
  unsigned short* WgT = (unsigned short*)(ws + WS_WGT);
  unsigned short* WuT = (unsigned short*)(ws + WS_WUT);
  unsigned short* WdT = (unsigned short*)(ws + WS_WDT);
  unsigned short* Hb  = (unsigned short*)(ws + WS_HB);
  int* eid      = (int*)(ws + WS_EID);
  int* tokofrow = (int*)(ws + WS_TOK);
  int* offsets  = (int*)(ws + WS_OFF);   // [9]
  int* tileOff  = offsets + 16;          // [9]  128-gran
  int* blockCnt = (int*)(ws + WS_BC);    // [1024][8]
  int* blockBase= (int*)(ws + WS_BB);    // [1024][8]

  k_route<<<1024, 256, 0, stream>>>(mu, tok, mrw, eid, blockCnt);
  k_scan2<<<1, 1024, 0, stream>>>(blockCnt, blockBase, offsets, tileOff);
  k_gathtr<<<3072, 256, 0, stream>>>(hs, eid, blockBase, tokofrow, Xs,
                                     wg, wu, WgT, WuT);
  // gemm1 (540 tiles) + Wd-transpose tail (512 blocks) in one dispatch
  k_gemm1<<<1052, 512, 0, stream>>>(Xs, WgT, WuT, Hb, offsets, tileOff, wd, WdT);
  // gemm2: 135 x8 n-tiles = 1080
  k_gemm2<<<135 * 8, 512, 0, stream>>>(Hb, WdT, out, offsets, tileOff, tokofrow);
}